// Round 5
// baseline (195.662 us; speedup 1.0000x reference)
//
#include <hip/hip_runtime.h>
#include <math.h>

#define NT 256
#define RPB 128         // rows per block
#define NR 4            // rows per thread (strided by 32)

// jax.nn.softplus(x) = max(x,0) + log1p(exp(-|x|))
__device__ __forceinline__ float softplus_f(float v) {
    return fmaxf(v, 0.0f) + log1pf(expf(-fabsf(v)));
}

// ---- d_ws layout (float offsets) ----
// WS_WC: [68][72]; rows 0..63: cols 0..63 = sp(EX)-sp(IN), cols 64..71 = sp(w_hid2out)
//                  rows 64..67: cols 0..63 = C = M - sp(w_in2hid), cols 64..71 = 0
#define WS_WC   0
#define WS_HT   4896      // [8][68]: HT[q][k] = sp(w_hid2out[k][q]); cols 64..67 zero
#define WS_P4   5440      // [64] a^4, a = dec_hid - deg
#define WS_Q    5504      // [64] 1+a+a^2+a^3
#define WS_TH   5568      // [64] th_hid
#define WS_SM   5632      // dec_in[4] th_in[4] dec_out[8] th_out[8]
#define WS_TOT  5664

// prep: 20 blocks. 0..17: W-rows slice; 18: HT + pads + scalars; 19: gap junctions
__global__ __launch_bounds__(NT) void twc_prep(
    const float* __restrict__ w_in2hid,
    const float* __restrict__ w_hid_IN,
    const float* __restrict__ w_hid_EX,
    const float* __restrict__ w_hid2out,
    const float* __restrict__ gj_w,
    const float* __restrict__ th_in,
    const float* __restrict__ dec_in,
    const float* __restrict__ th_hid,
    const float* __restrict__ dec_hid,
    const float* __restrict__ th_out,
    const float* __restrict__ dec_out,
    const int* __restrict__ gj_src,
    const int* __restrict__ gj_dst,
    float* __restrict__ ws)
{
    const int t = threadIdx.x;
    const int blk = blockIdx.x;
    if (blk < 18) {
        const int i = blk * NT + t;          // 0..4607 = 64 rows x 72 cols
        if (i < 4608) {
            const int k = i / 72;
            const int j = i - k * 72;
            float v;
            if (j < 64) v = softplus_f(w_hid_EX[k * 64 + j]) - softplus_f(w_hid_IN[k * 64 + j]);
            else        v = softplus_f(w_hid2out[k * 8 + (j - 64)]);
            ws[WS_WC + i] = v;
        }
    } else if (blk == 18) {
        for (int i = t; i < 544; i += NT) {  // HT[8][68]
            const int q = i / 68, c = i - q * 68;
            ws[WS_HT + i] = (c < 64) ? softplus_f(w_hid2out[c * 8 + q]) : 0.0f;
        }
        if (t < 32) ws[WS_WC + (64 + (t >> 3)) * 72 + 64 + (t & 7)] = 0.0f;
        if (t < 4) { ws[WS_SM + t] = dec_in[t];      ws[WS_SM + 4 + t]  = th_in[t]; }
        if (t < 8) { ws[WS_SM + 8 + t] = dec_out[t]; ws[WS_SM + 16 + t] = th_out[t]; }
    } else {
        __shared__ float sw[128];
        __shared__ int ssrc[128], sdst[128];
        if (t < 128) { sw[t] = softplus_f(gj_w[t]); ssrc[t] = gj_src[t]; sdst[t] = gj_dst[t]; }
        __syncthreads();
        if (t < 64) {
            const int j = t;
            float m0 = 0.f, m1 = 0.f, m2 = 0.f, m3 = 0.f, deg = 0.f;
            #pragma unroll 4
            for (int e = 0; e < 128; ++e) {
                const float w = (sdst[e] == j) ? sw[e] : 0.0f;
                deg += w;
                const int se = ssrc[e];
                m0 += (se == 0) ? w : 0.0f;
                m1 += (se == 1) ? w : 0.0f;
                m2 += (se == 2) ? w : 0.0f;
                m3 += (se == 3) ? w : 0.0f;
            }
            ws[WS_WC + (64 + 0) * 72 + j] = m0 - softplus_f(w_in2hid[0 * 64 + j]);
            ws[WS_WC + (64 + 1) * 72 + j] = m1 - softplus_f(w_in2hid[1 * 64 + j]);
            ws[WS_WC + (64 + 2) * 72 + j] = m2 - softplus_f(w_in2hid[2 * 64 + j]);
            ws[WS_WC + (64 + 3) * 72 + j] = m3 - softplus_f(w_in2hid[3 * 64 + j]);
            const float a  = dec_hid[j] - deg;
            const float a2 = a * a;
            ws[WS_P4 + j] = a2 * a2;
            ws[WS_Q + j]  = 1.0f + a + a2 + a2 * a;
            ws[WS_TH + j] = th_hid[j];
        }
    }
}

#define FMA8(I0, I1, W0, W1, A)                         \
    I0.x = fmaf(A, W0.x, I0.x); I0.y = fmaf(A, W0.y, I0.y); \
    I0.z = fmaf(A, W0.z, I0.z); I0.w = fmaf(A, W0.w, I0.w); \
    I1.x = fmaf(A, W1.x, I1.x); I1.y = fmaf(A, W1.y, I1.y); \
    I1.z = fmaf(A, W1.z, I1.z); I1.w = fmaf(A, W1.w, I1.w);

__global__ __launch_bounds__(NT, 6) void twc_main(
    const float* __restrict__ x,
    const float* __restrict__ hidE0,
    const float* __restrict__ hidO0,
    const float* __restrict__ outE0,
    const float* __restrict__ ws,
    float* __restrict__ out, int B)
{
    __shared__ __align__(16) float4 s4[1360];   // weights [68][18] + HT [8][17] = 21760 B
    const float4* ws4 = (const float4*)ws;
    const int t = threadIdx.x;
    const int r = t >> 3;            // 0..31
    const int q = t & 7;             // 0..7
    const size_t rowBase = (size_t)blockIdx.x * RPB;
    const size_t Bs = (size_t)B;
    float4* out4 = (float4*)out;

    // ---- coop stage weights into LDS ----
    for (int i = t; i < 1360; i += NT) s4[i] = ws4[i];

    // ---- E_in / O_in (no LDS dependency; overlaps the staging sync) ----
    if (t < 128) {
        const float4 xv = ((const float4*)x)[rowBase + t];
        const float4 di = ws4[1408];   // dec_in
        const float4 ti = ws4[1409];   // th_in
        float4 Ein, Oin;
        Ein.x = di.x * xv.x; Ein.y = di.y * xv.y; Ein.z = di.z * xv.z; Ein.w = di.w * xv.w;
        Oin.x = (Ein.x >= ti.x) ? Ein.x : 0.0f;
        Oin.y = (Ein.y >= ti.y) ? Ein.y : 0.0f;
        Oin.z = (Ein.z >= ti.z) ? Ein.z : 0.0f;
        Oin.w = (Ein.w >= ti.w) ? Ein.w : 0.0f;
        out4[Bs * 2 + rowBase + t] = Ein;
        out4[Bs * 3 + rowBase + t] = Oin;
    }
    __syncthreads();

    // ---- k-loop: I[i][8cols] += O0row@W, h2o[i] += O0row@H ----
    float4 I0a, I0b, I1a, I1b, I2a, I2b, I3a, I3b;
    I0a = I0b = I1a = I1b = I2a = I2b = I3a = I3b = float4{0.f, 0.f, 0.f, 0.f};
    float h2o0 = 0.f, h2o1 = 0.f, h2o2 = 0.f, h2o3 = 0.f;

    const int wq = 2 * q;
    const size_t ro = rowBase + r;               // rows ro + 32*i
    const float4* O04 = (const float4*)hidO0;

    #pragma unroll 2
    for (int kk = 0; kk < 16; ++kk) {
        const float4 o0 = O04[(ro +  0) * 16 + kk];
        const float4 o1 = O04[(ro + 32) * 16 + kk];
        const float4 o2 = O04[(ro + 64) * 16 + kk];
        const float4 o3 = O04[(ro + 96) * 16 + kk];
        const float4 ht = s4[1224 + q * 17 + kk];
        #pragma unroll
        for (int d = 0; d < 4; ++d) {
            const int k = 4 * kk + d;
            const float4 w0 = s4[k * 18 + wq];
            const float4 w1 = s4[k * 18 + wq + 1];
            const float hk = (d == 0) ? ht.x : (d == 1) ? ht.y : (d == 2) ? ht.z : ht.w;
            const float a0 = (d == 0) ? o0.x : (d == 1) ? o0.y : (d == 2) ? o0.z : o0.w;
            const float a1 = (d == 0) ? o1.x : (d == 1) ? o1.y : (d == 2) ? o1.z : o1.w;
            const float a2 = (d == 0) ? o2.x : (d == 1) ? o2.y : (d == 2) ? o2.z : o2.w;
            const float a3 = (d == 0) ? o3.x : (d == 1) ? o3.y : (d == 2) ? o3.z : o3.w;
            FMA8(I0a, I0b, w0, w1, a0); h2o0 = fmaf(a0, hk, h2o0);
            FMA8(I1a, I1b, w0, w1, a1); h2o1 = fmaf(a1, hk, h2o1);
            FMA8(I2a, I2b, w0, w1, a2); h2o2 = fmaf(a2, hk, h2o2);
            FMA8(I3a, I3b, w0, w1, a3); h2o3 = fmaf(a3, hk, h2o3);
        }
    }
    // ---- tail: x @ C (C = W rows 64..67); x via 8-way-broadcast global f4 ----
    {
        const float4 x0 = ((const float4*)x)[ro +  0];
        const float4 x1 = ((const float4*)x)[ro + 32];
        const float4 x2 = ((const float4*)x)[ro + 64];
        const float4 x3 = ((const float4*)x)[ro + 96];
        #pragma unroll
        for (int d = 0; d < 4; ++d) {
            const float4 w0 = s4[(64 + d) * 18 + wq];
            const float4 w1 = s4[(64 + d) * 18 + wq + 1];
            const float a0 = (d == 0) ? x0.x : (d == 1) ? x0.y : (d == 2) ? x0.z : x0.w;
            const float a1 = (d == 0) ? x1.x : (d == 1) ? x1.y : (d == 2) ? x1.z : x1.w;
            const float a2 = (d == 0) ? x2.x : (d == 1) ? x2.y : (d == 2) ? x2.z : x2.w;
            const float a3 = (d == 0) ? x3.x : (d == 1) ? x3.y : (d == 2) ? x3.z : x3.w;
            FMA8(I0a, I0b, w0, w1, a0);
            FMA8(I1a, I1b, w0, w1, a1);
            FMA8(I2a, I2b, w0, w1, a2);
            FMA8(I3a, I3b, w0, w1, a3);
        }
    }

    // ---- E_hid / O_hid: direct global f4 (dense over wq/wq+1 instr pair) ----
    {
        const float4 p0  = ws4[1360 + wq], p1  = ws4[1360 + wq + 1];   // a^4
        const float4 qv0 = ws4[1376 + wq], qv1 = ws4[1376 + wq + 1];   // sum a^i
        const float4 th0 = ws4[1392 + wq], th1 = ws4[1392 + wq + 1];   // th_hid
        const float4* gE0 = (const float4*)hidE0;
        #pragma unroll
        for (int i = 0; i < NR; ++i) {
            const size_t rho = ro + 32 * i;
            const float4 e0a = gE0[rho * 16 + wq];
            const float4 e0b = gE0[rho * 16 + wq + 1];
            const float4 Ia = (i == 0) ? I0a : (i == 1) ? I1a : (i == 2) ? I2a : I3a;
            const float4 Ib = (i == 0) ? I0b : (i == 1) ? I1b : (i == 2) ? I2b : I3b;
            float4 Ea, Eb, Oa, Ob;
            Ea.x = fmaf(p0.x, e0a.x, qv0.x * Ia.x);
            Ea.y = fmaf(p0.y, e0a.y, qv0.y * Ia.y);
            Ea.z = fmaf(p0.z, e0a.z, qv0.z * Ia.z);
            Ea.w = fmaf(p0.w, e0a.w, qv0.w * Ia.w);
            Eb.x = fmaf(p1.x, e0b.x, qv1.x * Ib.x);
            Eb.y = fmaf(p1.y, e0b.y, qv1.y * Ib.y);
            Eb.z = fmaf(p1.z, e0b.z, qv1.z * Ib.z);
            Eb.w = fmaf(p1.w, e0b.w, qv1.w * Ib.w);
            Oa.x = (Ea.x >= th0.x) ? Ea.x : 0.0f;
            Oa.y = (Ea.y >= th0.y) ? Ea.y : 0.0f;
            Oa.z = (Ea.z >= th0.z) ? Ea.z : 0.0f;
            Oa.w = (Ea.w >= th0.w) ? Ea.w : 0.0f;
            Ob.x = (Eb.x >= th1.x) ? Eb.x : 0.0f;
            Ob.y = (Eb.y >= th1.y) ? Eb.y : 0.0f;
            Ob.z = (Eb.z >= th1.z) ? Eb.z : 0.0f;
            Ob.w = (Eb.w >= th1.w) ? Eb.w : 0.0f;
            out4[Bs * 4  + rho * 16 + wq]     = Ea;
            out4[Bs * 4  + rho * 16 + wq + 1] = Eb;
            out4[Bs * 20 + rho * 16 + wq]     = Oa;
            out4[Bs * 20 + rho * 16 + wq + 1] = Ob;
        }
    }

    // ---- output layer: scalar per (row, q) — dense 1KB/wave stores, no LDS ----
    {
        const float dq  = ws[WS_SM + 8 + q];
        const float tho = ws[WS_SM + 16 + q];
        #pragma unroll
        for (int i = 0; i < NR; ++i) {
            const size_t rho = ro + 32 * i;
            const float hv = (i == 0) ? h2o0 : (i == 1) ? h2o1 : (i == 2) ? h2o2 : h2o3;
            const float e0 = outE0[rho * 8 + q];
            const float eo = fmaf(dq, e0, hv);
            out[rho * 8 + q]            = tanhf(eo);
            out[Bs * 144 + rho * 8 + q] = eo;
            out[Bs * 152 + rho * 8 + q] = (eo >= tho) ? eo : 0.0f;
        }
    }
}

extern "C" void kernel_launch(void* const* d_in, const int* in_sizes, int n_in,
                              void* d_out, int out_size, void* d_ws, size_t ws_size,
                              hipStream_t stream) {
    (void)n_in; (void)out_size; (void)ws_size;
    const float* x        = (const float*)d_in[0];
    const float* hidE0    = (const float*)d_in[1];
    const float* hidO0    = (const float*)d_in[2];
    const float* outE0    = (const float*)d_in[3];
    // d_in[4] (out_O0) unused by the reference
    const float* w_in2hid = (const float*)d_in[5];
    const float* w_hid_IN = (const float*)d_in[6];
    const float* w_hid_EX = (const float*)d_in[7];
    const float* w_hid2out= (const float*)d_in[8];
    const float* gj_w     = (const float*)d_in[9];
    const float* th_in    = (const float*)d_in[10];
    const float* dec_in   = (const float*)d_in[11];
    const float* th_hid   = (const float*)d_in[12];
    const float* dec_hid  = (const float*)d_in[13];
    const float* th_out   = (const float*)d_in[14];
    const float* dec_out  = (const float*)d_in[15];
    const int*   gj_src   = (const int*)d_in[16];
    const int*   gj_dst   = (const int*)d_in[17];
    float* out = (float*)d_out;
    float* ws  = (float*)d_ws;

    const int B = in_sizes[0] / 4;   // 262144, multiple of 128

    twc_prep<<<20, NT, 0, stream>>>(
        w_in2hid, w_hid_IN, w_hid_EX, w_hid2out, gj_w,
        th_in, dec_in, th_hid, dec_hid, th_out, dec_out,
        gj_src, gj_dst, ws);

    twc_main<<<B / RPB, NT, 0, stream>>>(x, hidE0, hidO0, outE0, ws, out, B);
}

// Round 6
// 97.141 us; speedup vs baseline: 2.0142x; 2.0142x over previous
//
#include <hip/hip_runtime.h>
#include <math.h>

#define NT 256
#define RPB 128         // rows per block
#define NR 4            // rows per thread (strided by 32)

// jax.nn.softplus(x) = max(x,0) + log1p(exp(-|x|))
__device__ __forceinline__ float softplus_f(float v) {
    return fmaxf(v, 0.0f) + log1pf(expf(-fabsf(v)));
}

// ---- d_ws layout (float offsets) ----
// WS_WC: [68][72]; rows 0..63: cols 0..63 = sp(EX)-sp(IN), cols 64..71 = sp(w_hid2out)
//                  rows 64..67: cols 0..63 = C = M - sp(w_in2hid), cols 64..71 = 0
#define WS_WC   0
#define WS_HT   4896      // [8][68]: HT[q][k] = sp(w_hid2out[k][q]); cols 64..67 zero
#define WS_P4   5440      // [64] a^4, a = dec_hid - deg
#define WS_Q    5504      // [64] 1+a+a^2+a^3
#define WS_TH   5568      // [64] th_hid
#define WS_SM   5632      // dec_in[4] th_in[4] dec_out[8] th_out[8]
#define WS_TOT  5664

// ---- main LDS layout (float4 indices) ----
#define LW   0            // [68][16] f4: W rows 0..63, C rows 64..67 (stride 16, no pad)
#define LHT  1088         // [8][17] f4: HT (pad 17 to break same-bank broadcast)
#define LT   1224         // [128][16] f4: O0 tile / E transpose buffer, rotation-swizzled
#define LDS_F4 3272       // 52352 bytes -> 3 blocks/CU

// prep: 20 blocks. 0..17: W-rows slice; 18: HT + pads + scalars; 19: gap junctions
__global__ __launch_bounds__(NT) void twc_prep(
    const float* __restrict__ w_in2hid,
    const float* __restrict__ w_hid_IN,
    const float* __restrict__ w_hid_EX,
    const float* __restrict__ w_hid2out,
    const float* __restrict__ gj_w,
    const float* __restrict__ th_in,
    const float* __restrict__ dec_in,
    const float* __restrict__ th_hid,
    const float* __restrict__ dec_hid,
    const float* __restrict__ th_out,
    const float* __restrict__ dec_out,
    const int* __restrict__ gj_src,
    const int* __restrict__ gj_dst,
    float* __restrict__ ws)
{
    const int t = threadIdx.x;
    const int blk = blockIdx.x;
    if (blk < 18) {
        const int i = blk * NT + t;          // 0..4607 = 64 rows x 72 cols
        if (i < 4608) {
            const int k = i / 72;
            const int j = i - k * 72;
            float v;
            if (j < 64) v = softplus_f(w_hid_EX[k * 64 + j]) - softplus_f(w_hid_IN[k * 64 + j]);
            else        v = softplus_f(w_hid2out[k * 8 + (j - 64)]);
            ws[WS_WC + i] = v;
        }
    } else if (blk == 18) {
        for (int i = t; i < 544; i += NT) {  // HT[8][68]
            const int q = i / 68, c = i - q * 68;
            ws[WS_HT + i] = (c < 64) ? softplus_f(w_hid2out[c * 8 + q]) : 0.0f;
        }
        if (t < 32) ws[WS_WC + (64 + (t >> 3)) * 72 + 64 + (t & 7)] = 0.0f;
        if (t < 4) { ws[WS_SM + t] = dec_in[t];      ws[WS_SM + 4 + t]  = th_in[t]; }
        if (t < 8) { ws[WS_SM + 8 + t] = dec_out[t]; ws[WS_SM + 16 + t] = th_out[t]; }
    } else {
        __shared__ float sw[128];
        __shared__ int ssrc[128], sdst[128];
        if (t < 128) { sw[t] = softplus_f(gj_w[t]); ssrc[t] = gj_src[t]; sdst[t] = gj_dst[t]; }
        __syncthreads();
        if (t < 64) {
            const int j = t;
            float m0 = 0.f, m1 = 0.f, m2 = 0.f, m3 = 0.f, deg = 0.f;
            #pragma unroll 4
            for (int e = 0; e < 128; ++e) {
                const float w = (sdst[e] == j) ? sw[e] : 0.0f;
                deg += w;
                const int se = ssrc[e];
                m0 += (se == 0) ? w : 0.0f;
                m1 += (se == 1) ? w : 0.0f;
                m2 += (se == 2) ? w : 0.0f;
                m3 += (se == 3) ? w : 0.0f;
            }
            ws[WS_WC + (64 + 0) * 72 + j] = m0 - softplus_f(w_in2hid[0 * 64 + j]);
            ws[WS_WC + (64 + 1) * 72 + j] = m1 - softplus_f(w_in2hid[1 * 64 + j]);
            ws[WS_WC + (64 + 2) * 72 + j] = m2 - softplus_f(w_in2hid[2 * 64 + j]);
            ws[WS_WC + (64 + 3) * 72 + j] = m3 - softplus_f(w_in2hid[3 * 64 + j]);
            const float a  = dec_hid[j] - deg;
            const float a2 = a * a;
            ws[WS_P4 + j] = a2 * a2;
            ws[WS_Q + j]  = 1.0f + a + a2 + a2 * a;
            ws[WS_TH + j] = th_hid[j];
        }
    }
}

#define FMA8(I0, I1, W0, W1, A)                         \
    I0.x = fmaf(A, W0.x, I0.x); I0.y = fmaf(A, W0.y, I0.y); \
    I0.z = fmaf(A, W0.z, I0.z); I0.w = fmaf(A, W0.w, I0.w); \
    I1.x = fmaf(A, W1.x, I1.x); I1.y = fmaf(A, W1.y, I1.y); \
    I1.z = fmaf(A, W1.z, I1.z); I1.w = fmaf(A, W1.w, I1.w);

__global__ __launch_bounds__(NT, 3) void twc_main(
    const float* __restrict__ x,
    const float* __restrict__ hidE0,
    const float* __restrict__ hidO0,
    const float* __restrict__ outE0,
    const float* __restrict__ ws,
    float* __restrict__ out, int B)
{
    __shared__ __align__(16) float4 s4[LDS_F4];
    const float4* ws4 = (const float4*)ws;
    const int t = threadIdx.x;
    const int r = t >> 3;            // 0..31
    const int q = t & 7;             // 0..7
    const size_t rowBase = (size_t)blockIdx.x * RPB;
    const size_t Bs = (size_t)B;
    float4* out4 = (float4*)out;

    // ---- stage W/C (repack stride 18 f4 -> 16 f4), HT, O0 tile (swizzled) ----
    for (int i = t; i < 1088; i += NT)
        s4[LW + i] = ws4[(i >> 4) * 18 + (i & 15)];
    if (t < 136) s4[LHT + t] = ws4[1224 + t];
    {
        const float4* gO0 = (const float4*)hidO0 + rowBase * 16;
        #pragma unroll
        for (int j = 0; j < 8; ++j) {
            const int i = j * NT + t;
            const int row = i >> 4, c = i & 15;
            s4[LT + row * 16 + ((c + row) & 15)] = gO0[i];
        }
    }

    // ---- E_in / O_in (dense, no LDS dependency) ----
    if (t < 128) {
        const float4 xv = ((const float4*)x)[rowBase + t];
        const float4 di = ws4[1408];   // dec_in
        const float4 ti = ws4[1409];   // th_in
        float4 Ein, Oin;
        Ein.x = di.x * xv.x; Ein.y = di.y * xv.y; Ein.z = di.z * xv.z; Ein.w = di.w * xv.w;
        Oin.x = (Ein.x >= ti.x) ? Ein.x : 0.0f;
        Oin.y = (Ein.y >= ti.y) ? Ein.y : 0.0f;
        Oin.z = (Ein.z >= ti.z) ? Ein.z : 0.0f;
        Oin.w = (Ein.w >= ti.w) ? Ein.w : 0.0f;
        out4[Bs * 2 + rowBase + t] = Ein;
        out4[Bs * 3 + rowBase + t] = Oin;
    }
    __syncthreads();

    // ---- k-loop: I[i][8cols] += O0row@W, h2o[i] += O0row@H ----
    float4 I0a, I0b, I1a, I1b, I2a, I2b, I3a, I3b;
    I0a = I0b = I1a = I1b = I2a = I2b = I3a = I3b = float4{0.f, 0.f, 0.f, 0.f};
    float h2o0 = 0.f, h2o1 = 0.f, h2o2 = 0.f, h2o3 = 0.f;

    const int wq = 2 * q;
    const size_t ro = rowBase + r;
    const int tb0 = LT + r * 16;     // +512 per 32-row step

    #pragma unroll 2
    for (int kk = 0; kk < 16; ++kk) {
        const int sl = (kk + r) & 15;            // rotation slot (same for all 4 rows)
        const float4 o0 = s4[tb0 + sl];
        const float4 o1 = s4[tb0 + 512 + sl];
        const float4 o2 = s4[tb0 + 1024 + sl];
        const float4 o3 = s4[tb0 + 1536 + sl];
        const float4 ht = s4[LHT + q * 17 + kk];
        #pragma unroll
        for (int d = 0; d < 4; ++d) {
            const int k = 4 * kk + d;
            const float4 w0 = s4[LW + k * 16 + wq];
            const float4 w1 = s4[LW + k * 16 + wq + 1];
            const float hk = (d == 0) ? ht.x : (d == 1) ? ht.y : (d == 2) ? ht.z : ht.w;
            const float a0 = (d == 0) ? o0.x : (d == 1) ? o0.y : (d == 2) ? o0.z : o0.w;
            const float a1 = (d == 0) ? o1.x : (d == 1) ? o1.y : (d == 2) ? o1.z : o1.w;
            const float a2 = (d == 0) ? o2.x : (d == 1) ? o2.y : (d == 2) ? o2.z : o2.w;
            const float a3 = (d == 0) ? o3.x : (d == 1) ? o3.y : (d == 2) ? o3.z : o3.w;
            FMA8(I0a, I0b, w0, w1, a0); h2o0 = fmaf(a0, hk, h2o0);
            FMA8(I1a, I1b, w0, w1, a1); h2o1 = fmaf(a1, hk, h2o1);
            FMA8(I2a, I2b, w0, w1, a2); h2o2 = fmaf(a2, hk, h2o2);
            FMA8(I3a, I3b, w0, w1, a3); h2o3 = fmaf(a3, hk, h2o3);
        }
    }
    // ---- tail: x @ C (C = W rows 64..67); x direct (dense 16B rows) ----
    {
        const float4 x0 = ((const float4*)x)[ro +  0];
        const float4 x1 = ((const float4*)x)[ro + 32];
        const float4 x2 = ((const float4*)x)[ro + 64];
        const float4 x3 = ((const float4*)x)[ro + 96];
        #pragma unroll
        for (int d = 0; d < 4; ++d) {
            const float4 w0 = s4[LW + (64 + d) * 16 + wq];
            const float4 w1 = s4[LW + (64 + d) * 16 + wq + 1];
            const float a0 = (d == 0) ? x0.x : (d == 1) ? x0.y : (d == 2) ? x0.z : x0.w;
            const float a1 = (d == 0) ? x1.x : (d == 1) ? x1.y : (d == 2) ? x1.z : x1.w;
            const float a2 = (d == 0) ? x2.x : (d == 1) ? x2.y : (d == 2) ? x2.z : x2.w;
            const float a3 = (d == 0) ? x3.x : (d == 1) ? x3.y : (d == 2) ? x3.z : x3.w;
            FMA8(I0a, I0b, w0, w1, a0);
            FMA8(I1a, I1b, w0, w1, a1);
            FMA8(I2a, I2b, w0, w1, a2);
            FMA8(I3a, I3b, w0, w1, a3);
        }
    }
    __syncthreads();   // all O0 tile reads complete

    // ---- E_hid into tile (swizzled own slots); E0 read direct (paired 16B ok) ----
    {
        const float4 p0  = ws4[1360 + wq], p1  = ws4[1360 + wq + 1];   // a^4
        const float4 qv0 = ws4[1376 + wq], qv1 = ws4[1376 + wq + 1];   // sum a^i
        const float4* gE0 = (const float4*)hidE0;
        #pragma unroll
        for (int i = 0; i < NR; ++i) {
            const size_t rho = ro + 32 * i;
            const int rl = r + 32 * i;
            const float4 e0a = gE0[rho * 16 + wq];
            const float4 e0b = gE0[rho * 16 + wq + 1];
            const float4 Ia = (i == 0) ? I0a : (i == 1) ? I1a : (i == 2) ? I2a : I3a;
            const float4 Ib = (i == 0) ? I0b : (i == 1) ? I1b : (i == 2) ? I2b : I3b;
            float4 Ea, Eb;
            Ea.x = fmaf(p0.x, e0a.x, qv0.x * Ia.x);
            Ea.y = fmaf(p0.y, e0a.y, qv0.y * Ia.y);
            Ea.z = fmaf(p0.z, e0a.z, qv0.z * Ia.z);
            Ea.w = fmaf(p0.w, e0a.w, qv0.w * Ia.w);
            Eb.x = fmaf(p1.x, e0b.x, qv1.x * Ib.x);
            Eb.y = fmaf(p1.y, e0b.y, qv1.y * Ib.y);
            Eb.z = fmaf(p1.z, e0b.z, qv1.z * Ib.z);
            Eb.w = fmaf(p1.w, e0b.w, qv1.w * Ib.w);
            s4[LT + rl * 16 + ((wq + rl) & 15)]     = Ea;
            s4[LT + rl * 16 + ((wq + 1 + rl) & 15)] = Eb;
        }
    }

    // ---- output layer: scalar per (row,q) — dense 256B/wave stores ----
    {
        const float dq  = ws[WS_SM + 8 + q];
        const float tho = ws[WS_SM + 16 + q];
        #pragma unroll
        for (int i = 0; i < NR; ++i) {
            const size_t rho = ro + 32 * i;
            const float hv = (i == 0) ? h2o0 : (i == 1) ? h2o1 : (i == 2) ? h2o2 : h2o3;
            const float e0 = outE0[rho * 8 + q];
            const float eo = fmaf(dq, e0, hv);
            out[rho * 8 + q]            = tanhf(eo);
            out[Bs * 144 + rho * 8 + q] = eo;
            out[Bs * 152 + rho * 8 + q] = (eo >= tho) ? eo : 0.0f;
        }
    }
    __syncthreads();   // E tile complete

    // ---- copy-out: dense f4 stores; O_hid = gate(E) on the fly ----
    #pragma unroll
    for (int j = 0; j < 8; ++j) {
        const int i = j * NT + t;
        const int row = i >> 4, c = i & 15;
        const float4 E  = s4[LT + row * 16 + ((c + row) & 15)];
        const float4 th = ws4[1392 + c];
        float4 O;
        O.x = (E.x >= th.x) ? E.x : 0.0f;
        O.y = (E.y >= th.y) ? E.y : 0.0f;
        O.z = (E.z >= th.z) ? E.z : 0.0f;
        O.w = (E.w >= th.w) ? E.w : 0.0f;
        out4[Bs * 4  + rowBase * 16 + i] = E;
        out4[Bs * 20 + rowBase * 16 + i] = O;
    }
}

extern "C" void kernel_launch(void* const* d_in, const int* in_sizes, int n_in,
                              void* d_out, int out_size, void* d_ws, size_t ws_size,
                              hipStream_t stream) {
    (void)n_in; (void)out_size; (void)ws_size;
    const float* x        = (const float*)d_in[0];
    const float* hidE0    = (const float*)d_in[1];
    const float* hidO0    = (const float*)d_in[2];
    const float* outE0    = (const float*)d_in[3];
    // d_in[4] (out_O0) unused by the reference
    const float* w_in2hid = (const float*)d_in[5];
    const float* w_hid_IN = (const float*)d_in[6];
    const float* w_hid_EX = (const float*)d_in[7];
    const float* w_hid2out= (const float*)d_in[8];
    const float* gj_w     = (const float*)d_in[9];
    const float* th_in    = (const float*)d_in[10];
    const float* dec_in   = (const float*)d_in[11];
    const float* th_hid   = (const float*)d_in[12];
    const float* dec_hid  = (const float*)d_in[13];
    const float* th_out   = (const float*)d_in[14];
    const float* dec_out  = (const float*)d_in[15];
    const int*   gj_src   = (const int*)d_in[16];
    const int*   gj_dst   = (const int*)d_in[17];
    float* out = (float*)d_out;
    float* ws  = (float*)d_ws;

    const int B = in_sizes[0] / 4;   // 262144, multiple of 128

    twc_prep<<<20, NT, 0, stream>>>(
        w_in2hid, w_hid_IN, w_hid_EX, w_hid2out, gj_w,
        th_in, dec_in, th_hid, dec_hid, th_out, dec_out,
        gj_src, gj_dst, ws);

    twc_main<<<B / RPB, NT, 0, stream>>>(x, hidE0, hidO0, outE0, ws, out, B);
}

// Round 7
// 78.094 us; speedup vs baseline: 2.5055x; 1.2439x over previous
//
#include <hip/hip_runtime.h>
#include <math.h>

#define NT 256
#define RPB 64          // rows per block; 4 waves x one 16-row MFMA tile

typedef __attribute__((ext_vector_type(8))) short bf16x8;   // 8 bf16 = 4 VGPR
typedef __attribute__((ext_vector_type(4))) float f32x4;    // MFMA 16x16 acc

// jax.nn.softplus(x) = max(x,0) + log1p(exp(-|x|))
__device__ __forceinline__ float softplus_f(float v) {
    return fmaxf(v, 0.0f) + log1pf(expf(-fabsf(v)));
}
__device__ __forceinline__ unsigned short bfr(float f) {    // f32 -> bf16 RNE
    unsigned int u = __float_as_uint(f);
    u += 0x7FFFu + ((u >> 16) & 1u);
    return (unsigned short)(u >> 16);
}
__device__ __forceinline__ unsigned int bfpack(float a, float b) {
    return (unsigned int)bfr(a) | ((unsigned int)bfr(b) << 16);
}

// ---- ws layout (dword offsets) ----
// [0,3840):   WT bf16 [80 col][96 k]:
//   col<64,k<64:  sp(EX[k][col]) - sp(IN[k][col])
//   col<64,k=64+d: C[d][col] = M[d][col] - sp(w_in2hid[d][col])
//   64<=col<72,k<64: sp(w_hid2out[k][col-64]);  all else 0
// [3840,3904): a^4   [3904,3968): 1+a+a^2+a^3   [3968,4032): th_hid
// [4032,4056): dec_in[4] th_in[4] dec_out[8] th_out[8]

__global__ __launch_bounds__(NT) void twc_prep(
    const float* __restrict__ w_in2hid,
    const float* __restrict__ w_hid_IN,
    const float* __restrict__ w_hid_EX,
    const float* __restrict__ w_hid2out,
    const float* __restrict__ gj_w,
    const float* __restrict__ th_in,
    const float* __restrict__ dec_in,
    const float* __restrict__ th_hid,
    const float* __restrict__ dec_hid,
    const float* __restrict__ th_out,
    const float* __restrict__ dec_out,
    const int* __restrict__ gj_src,
    const int* __restrict__ gj_dst,
    float* __restrict__ ws)
{
    const int t = threadIdx.x;
    const int blk = blockIdx.x;
    unsigned short* wsS = (unsigned short*)ws;
    if (blk < 30) {
        const int e = blk * NT + t;              // 0..7679 = 80 cols x 96 k
        const int col = e / 96, k = e - col * 96;
        if (col < 64 && k >= 64 && k < 68) return;   // C entries: block 30 owns
        float v = 0.0f;
        if (col < 64 && k < 64)
            v = softplus_f(w_hid_EX[k * 64 + col]) - softplus_f(w_hid_IN[k * 64 + col]);
        else if (col >= 64 && col < 72 && k < 64)
            v = softplus_f(w_hid2out[k * 8 + (col - 64)]);
        wsS[e] = bfr(v);
    } else {
        __shared__ float sw[128];
        __shared__ int ssrc[128], sdst[128];
        if (t < 128) { sw[t] = softplus_f(gj_w[t]); ssrc[t] = gj_src[t]; sdst[t] = gj_dst[t]; }
        __syncthreads();
        if (t < 64) {
            const int j = t;
            float m0 = 0.f, m1 = 0.f, m2 = 0.f, m3 = 0.f, deg = 0.f;
            #pragma unroll 4
            for (int e = 0; e < 128; ++e) {
                const float w = (sdst[e] == j) ? sw[e] : 0.0f;
                deg += w;
                const int se = ssrc[e];
                m0 += (se == 0) ? w : 0.0f;
                m1 += (se == 1) ? w : 0.0f;
                m2 += (se == 2) ? w : 0.0f;
                m3 += (se == 3) ? w : 0.0f;
            }
            wsS[j * 96 + 64] = bfr(m0 - softplus_f(w_in2hid[0 * 64 + j]));
            wsS[j * 96 + 65] = bfr(m1 - softplus_f(w_in2hid[1 * 64 + j]));
            wsS[j * 96 + 66] = bfr(m2 - softplus_f(w_in2hid[2 * 64 + j]));
            wsS[j * 96 + 67] = bfr(m3 - softplus_f(w_in2hid[3 * 64 + j]));
            const float a  = dec_hid[j] - deg;
            const float a2 = a * a;
            ws[3840 + j] = a2 * a2;
            ws[3904 + j] = 1.0f + a + a2 + a2 * a;
            ws[3968 + j] = th_hid[j];
        }
        if (t < 4) { ws[4032 + t] = dec_in[t];  ws[4036 + t] = th_in[t]; }
        if (t < 8) { ws[4040 + t] = dec_out[t]; ws[4048 + t] = th_out[t]; }
    }
}

// ---- main LDS (dwords): [0,3840) WT bf16; [3840,8704) buf:
//   k-loop phase: A bf16 [64 rows][96 k] (= 3072 dw)
//   epilogue:     E  f32 [64 rows][76]   (= 4864 dw)
__global__ __launch_bounds__(NT, 4) void twc_main(
    const float* __restrict__ x,
    const float* __restrict__ hidE0,
    const float* __restrict__ hidO0,
    const float* __restrict__ outE0,
    const float* __restrict__ ws,
    float* __restrict__ out, int B)
{
    __shared__ __align__(16) unsigned int slds[8704];
    const int t = threadIdx.x;
    const size_t rowBase = (size_t)blockIdx.x * RPB;
    const size_t Bs = (size_t)B;
    float4* out4 = (float4*)out;
    const float* wsf = ws;

    // ---- stage WT (960 f4, linear) ----
    {
        const float4* wsv = (const float4*)ws;
        float4* l4 = (float4*)slds;
        #pragma unroll
        for (int j = 0; j < 4; ++j) {
            const int i = j * NT + t;
            if (i < 960) l4[i] = wsv[i];
        }
    }
    // ---- stage A: O0 (dense f4 reads -> bf16), x into k64..67, zero k68..95 ----
    {
        const float4* gO0 = (const float4*)hidO0 + rowBase * 16;
        #pragma unroll
        for (int j = 0; j < 4; ++j) {
            const int i = j * NT + t;            // 1024 f4 = 64 rows x 16
            const float4 v = gO0[i];
            const int row = i >> 4, c4 = i & 15;
            const int base = 3840 + row * 48 + c4 * 2;
            slds[base]     = bfpack(v.x, v.y);
            slds[base + 1] = bfpack(v.z, v.w);
        }
        #pragma unroll
        for (int j = 0; j < 2; ++j) {
            const int i = j * NT + t;            // 448 zero b64 slots
            if (i < 448) {
                const int row = i / 7, p = i - row * 7;
                const int base = 3840 + row * 48 + 34 + p * 2;
                slds[base] = 0u; slds[base + 1] = 0u;
            }
        }
        if (t < 64) {
            const float4 xv = ((const float4*)x)[rowBase + t];
            const int base = 3840 + t * 48 + 32;
            slds[base]     = bfpack(xv.x, xv.y);
            slds[base + 1] = bfpack(xv.z, xv.w);
            // E_in / O_in (exact f32 path)
            const float4 di = ((const float4*)ws)[1008];
            const float4 ti = ((const float4*)ws)[1009];
            float4 Ein, Oin;
            Ein.x = di.x * xv.x; Ein.y = di.y * xv.y; Ein.z = di.z * xv.z; Ein.w = di.w * xv.w;
            Oin.x = (Ein.x >= ti.x) ? Ein.x : 0.0f;
            Oin.y = (Ein.y >= ti.y) ? Ein.y : 0.0f;
            Oin.z = (Ein.z >= ti.z) ? Ein.z : 0.0f;
            Oin.w = (Ein.w >= ti.w) ? Ein.w : 0.0f;
            out4[Bs * 2 + rowBase + t] = Ein;
            out4[Bs * 3 + rowBase + t] = Oin;
        }
    }
    __syncthreads();

    // ---- MFMA k-loop: D[64 rows][80 cols] = A[64][96] @ WT^T ----
    const int l = t & 63, w = t >> 6;
    const int fr = l & 15, lg = l >> 4;
    f32x4 acc[5];
    {
        const f32x4 z = {0.0f, 0.0f, 0.0f, 0.0f};
        #pragma unroll
        for (int ct = 0; ct < 5; ++ct) acc[ct] = z;
        const short* Ash = (const short*)(slds + 3840) + (w * 16 + fr) * 96 + lg * 8;
        const short* Bsh = (const short*)slds + fr * 96 + lg * 8;
        #pragma unroll
        for (int s = 0; s < 3; ++s) {
            const bf16x8 af = *(const bf16x8*)(Ash + s * 32);
            #pragma unroll
            for (int ct = 0; ct < 5; ++ct) {
                const bf16x8 bv = *(const bf16x8*)(Bsh + ct * 1536 + s * 32);
                acc[ct] = __builtin_amdgcn_mfma_f32_16x16x32_bf16(af, bv, acc[ct], 0, 0, 0);
            }
        }
    }
    __syncthreads();   // A consumed; buf region reused for E f32

    // ---- E_hid = a^4*E0 + (sum a^i)*I into buf; h2o into buf cols 64..71 ----
    {
        float* buf = (float*)(slds + 3840);
        const int rowl = w * 16 + lg * 4;
        #pragma unroll
        for (int ct = 0; ct < 4; ++ct) {
            const int c = ct * 16 + fr;
            const float p4 = wsf[3840 + c];
            const float qs = wsf[3904 + c];
            #pragma unroll
            for (int r = 0; r < 4; ++r) {
                const int row = rowl + r;
                const float e0 = hidE0[(rowBase + row) * 64 + c];
                buf[row * 76 + c] = fmaf(p4, e0, qs * acc[ct][r]);
            }
        }
        if (fr < 8) {
            #pragma unroll
            for (int r = 0; r < 4; ++r)
                buf[(rowl + r) * 76 + 64 + fr] = acc[4][r];
        }
    }
    __syncthreads();

    // ---- copy-out: dense f4 E/O_hid; dense scalar out-layer ----
    {
        const float* buf = (const float*)(slds + 3840);
        const float4* th4 = (const float4*)ws + 992;
        #pragma unroll
        for (int j = 0; j < 4; ++j) {
            const int i = j * NT + t;
            const int row = i >> 4, c4 = i & 15;
            const float4 E = *(const float4*)&buf[row * 76 + c4 * 4];
            const float4 th = th4[c4];
            float4 O;
            O.x = (E.x >= th.x) ? E.x : 0.0f;
            O.y = (E.y >= th.y) ? E.y : 0.0f;
            O.z = (E.z >= th.z) ? E.z : 0.0f;
            O.w = (E.w >= th.w) ? E.w : 0.0f;
            out4[Bs * 4  + rowBase * 16 + i] = E;
            out4[Bs * 20 + rowBase * 16 + i] = O;
        }
        #pragma unroll
        for (int j = 0; j < 2; ++j) {
            const int idx = j * NT + t;          // 512 = 64 rows x 8
            const int row = idx >> 3, q = idx & 7;
            const float h  = buf[row * 76 + 64 + q];
            const float e0 = outE0[rowBase * 8 + idx];
            const float eo = fmaf(wsf[4040 + q], e0, h);
            out[rowBase * 8 + idx]            = tanhf(eo);
            out[Bs * 144 + rowBase * 8 + idx] = eo;
            out[Bs * 152 + rowBase * 8 + idx] = (eo >= wsf[4048 + q]) ? eo : 0.0f;
        }
    }
}

extern "C" void kernel_launch(void* const* d_in, const int* in_sizes, int n_in,
                              void* d_out, int out_size, void* d_ws, size_t ws_size,
                              hipStream_t stream) {
    (void)n_in; (void)out_size; (void)ws_size;
    const float* x        = (const float*)d_in[0];
    const float* hidE0    = (const float*)d_in[1];
    const float* hidO0    = (const float*)d_in[2];
    const float* outE0    = (const float*)d_in[3];
    // d_in[4] (out_O0) unused by the reference
    const float* w_in2hid = (const float*)d_in[5];
    const float* w_hid_IN = (const float*)d_in[6];
    const float* w_hid_EX = (const float*)d_in[7];
    const float* w_hid2out= (const float*)d_in[8];
    const float* gj_w     = (const float*)d_in[9];
    const float* th_in    = (const float*)d_in[10];
    const float* dec_in   = (const float*)d_in[11];
    const float* th_hid   = (const float*)d_in[12];
    const float* dec_hid  = (const float*)d_in[13];
    const float* th_out   = (const float*)d_in[14];
    const float* dec_out  = (const float*)d_in[15];
    const int*   gj_src   = (const int*)d_in[16];
    const int*   gj_dst   = (const int*)d_in[17];
    float* out = (float*)d_out;
    float* ws  = (float*)d_ws;

    const int B = in_sizes[0] / 4;   // 262144, multiple of 64

    twc_prep<<<31, NT, 0, stream>>>(
        w_in2hid, w_hid_IN, w_hid_EX, w_hid2out, gj_w,
        th_in, dec_in, th_hid, dec_hid, th_out, dec_out,
        gj_src, gj_dst, ws);

    twc_main<<<B / RPB, NT, 0, stream>>>(x, hidE0, hidO0, outE0, ws, out, B);
}